// Round 11
// baseline (1338.194 us; speedup 1.0000x reference)
//
#include <hip/hip_runtime.h>

#define T 4096
#define EP 8                      // steps per barrier epoch
#define RING 32                   // qring depth; writer/reader residues disjoint mod 32
#define NEP (T / EP + 2)          // 514 epochs: wave1 lags wave0 by 2 epochs

// tanh(x) = 1 - 2/(exp(2x)+1). Branch-free; exonerated R2 vs R3.
__device__ __forceinline__ float fast_tanh(float x) {
    float e = __expf(2.0f * x);
    float r = __builtin_amdgcn_rcpf(e + 1.0f);
    return fmaf(-2.0f, r, 1.0f);
}

// v_readlane broadcast (SGPR result usable as the scalar FMA operand).
__device__ __forceinline__ float lane_bcast(float v, int j) {
    return __uint_as_float(__builtin_amdgcn_readlane(__float_as_uint(v), j));
}

// Opaque VGPR redefinition (keeps weight loads out of the hot loop).
#define PIN(x) asm volatile("" : "+v"(x))

// ---------------------------------------------------------------------------
// prep: pre[s][t][i] = b_ih0[i] + b_hh0[i] + sum_d W_ih0[i][d] * in[0,t,d]
// Only batch element 0 of x / y matters (reference uses e[0], o[0] only).
// ---------------------------------------------------------------------------
__global__ void prep_kernel(const float* __restrict__ x, const float* __restrict__ y,
                            const float* __restrict__ eW, const float* __restrict__ ebi,
                            const float* __restrict__ ebh,
                            const float* __restrict__ oW, const float* __restrict__ obi,
                            const float* __restrict__ obh,
                            float* __restrict__ pre)
{
    int idx = blockIdx.x * blockDim.x + threadIdx.x;   // 2*T*64 threads
    int i = idx & 63;
    int t = (idx >> 6) & (T - 1);
    int s = idx >> 18;
    const float* in = s ? y : x;          // batch 0 = first T*3 floats
    const float* W  = s ? oW : eW;        // [64][3]
    const float* bi = s ? obi : ebi;
    const float* bh = s ? obh : ebh;
    float v = bi[i] + bh[i]
            + W[i*3+0]*in[t*3+0] + W[i*3+1]*in[t*3+1] + W[i*3+2]*in[t*3+2];
    pre[idx] = v;
}

// ---------------------------------------------------------------------------
// seq: TWO waves per RNN, barrier once per EP(=8)-step epoch.
//   wave0 @ epoch k, t in [8k, 8k+8) (t<=T):
//     broadcast hp=h0[t-1] once (64 readlanes); TWO independent FMA streams:
//       a += Whh0[lane][j]*hj  and  q += Wih1[lane][j]*hj
//     publish qring[t-1] = b1 + q; hp = tanh(p[t] + a) (skipped at t==T —
//     the q-only tail step supplies q[T-1], R4-bugfix class).
//   wave1 @ epoch k, t' in [8(k-2), 8(k-2)+8):
//     h1[t'] = tanh(qring[t'] + Whh1@h1[t'-1])   (readlane recurrence)
//   hlast = h1[T-1] (written by wave1).
// qring residues mod 32: epoch-k writers {8k-1..8k+6}, readers {8k-16..8k-9}
// — disjoint for all k mod 4; readers always >=1 barrier behind.
// h0 never touches LDS; the q-FMA stream rides the SAME readlanes as the
// h0 recurrence and fills its hazard/tanh bubbles (R10 post-mortem: ~370
// cyc/step of serial-chain stall was the dominant cost).
// ---------------------------------------------------------------------------
__global__ __launch_bounds__(128, 1) void seq_kernel(
    const float* __restrict__ pre,            // [2][T][64]
    const float* __restrict__ eWhh0, const float* __restrict__ eWih1,
    const float* __restrict__ eWhh1, const float* __restrict__ ebih1,
    const float* __restrict__ ebhh1,
    const float* __restrict__ oWhh0, const float* __restrict__ oWih1,
    const float* __restrict__ oWhh1, const float* __restrict__ obih1,
    const float* __restrict__ obhh1,
    float* __restrict__ hlast)                // [2][64]
{
    const int s    = blockIdx.x;
    const int wv   = threadIdx.x >> 6;
    const int lane = threadIdx.x & 63;

    __shared__ __align__(16) float qring[RING][64];

    const float* p = pre + s * T * 64;

    if (wv == 0) {
        // ---------- layer-0 recurrence + full q projection ----------
        const float* Whh0 = s ? oWhh0 : eWhh0;
        const float* Wih1 = s ? oWih1 : eWih1;
        const float  b1   = s ? (obih1[lane] + obhh1[lane])
                              : (ebih1[lane] + ebhh1[lane]);
        float w0[64], wi[64];
#pragma unroll
        for (int j = 0; j < 64; ++j) w0[j] = Whh0[lane * 64 + j];
#pragma unroll
        for (int j = 0; j < 64; ++j) wi[j] = Wih1[lane * 64 + j];
#pragma unroll
        for (int j = 0; j < 64; ++j) { PIN(w0[j]); PIN(wi[j]); }

        float hp = 0.f;                        // h0[t-1]
        float pc[EP], pn[EP];
#pragma unroll
        for (int i = 0; i < EP; ++i) pc[i] = p[i * 64 + lane];

        for (int k = 0; k < NEP; ++k) {
            const int base = k * EP;
            // prefetch next epoch's p (consumed next epoch)
#pragma unroll
            for (int i = 0; i < EP; ++i) {
                int t = base + EP + i;
                pn[i] = (t < T) ? p[t * 64 + lane] : 0.f;
            }
            if (base <= T) {
#pragma unroll
                for (int i = 0; i < EP; ++i) {
                    const int t = base + i;
                    if (t <= T) {              // wave-uniform guard
                        float aa[4] = { pc[i], 0.f, 0.f, 0.f };
                        float qq[4] = { b1,    0.f, 0.f, 0.f };
#pragma unroll
                        for (int jb = 0; jb < 64; jb += 8) {
                            float hj[8];
#pragma unroll
                            for (int u = 0; u < 8; ++u) hj[u] = lane_bcast(hp, jb + u);
#pragma unroll
                            for (int u = 0; u < 8; ++u) {
                                aa[u & 3] = fmaf(w0[jb + u], hj[u], aa[u & 3]);
                                qq[u & 3] = fmaf(wi[jb + u], hj[u], qq[u & 3]);
                            }
                        }
                        qring[(t + RING - 1) & (RING - 1)][lane] =   // q[t-1]
                            (qq[0] + qq[1]) + (qq[2] + qq[3]);
                        if (t < T)
                            hp = fast_tanh((aa[0] + aa[1]) + (aa[2] + aa[3]));
                    }
                }
            }
#pragma unroll
            for (int i = 0; i < EP; ++i) pc[i] = pn[i];
            __syncthreads();
        }
    } else {
        // ---------- layer-1 recurrence wave ----------
        const float* Whh1 = s ? oWhh1 : eWhh1;
        float w1[64];
#pragma unroll
        for (int j = 0; j < 64; ++j) w1[j] = Whh1[lane * 64 + j];
#pragma unroll
        for (int j = 0; j < 64; ++j) PIN(w1[j]);

        float hp = 0.f;                        // h1[t'-1]
        for (int k = 0; k < NEP; ++k) {
            const int base = (k - 2) * EP;
            if (base >= 0 && base < T) {
                float qb[EP];
#pragma unroll
                for (int i = 0; i < EP; ++i)   // all written >=1 barrier ago
                    qb[i] = qring[(base + i) & (RING - 1)][lane];
#pragma unroll
                for (int i = 0; i < EP; ++i) {
                    float cc[4] = { qb[i], 0.f, 0.f, 0.f };
#pragma unroll
                    for (int jb = 0; jb < 64; jb += 8) {
                        float hj[8];
#pragma unroll
                        for (int u = 0; u < 8; ++u) hj[u] = lane_bcast(hp, jb + u);
#pragma unroll
                        for (int u = 0; u < 8; ++u)
                            cc[u & 3] = fmaf(w1[jb + u], hj[u], cc[u & 3]);
                    }
                    hp = fast_tanh((cc[0] + cc[1]) + (cc[2] + cc[3]));
                }
            }
            __syncthreads();
        }
        hlast[s * 64 + lane] = hp;             // h1[T-1]
    }
}

// ---------------------------------------------------------------------------
// head: e0 = fce_w@hx + fce_b ; o0 = fco_w@hy + fco_b ; zz=[e0,o0,z];
//       h = relu(fc1_w@zz + fc1_b) ; out = fc2_w@h + fc2_b
// ---------------------------------------------------------------------------
__global__ void head_kernel(const float* __restrict__ hlast,   // [2][64]
                            const float* __restrict__ z,
                            const float* __restrict__ fce_w, const float* __restrict__ fce_b,
                            const float* __restrict__ fco_w, const float* __restrict__ fco_b,
                            const float* __restrict__ fc1_w, const float* __restrict__ fc1_b,
                            const float* __restrict__ fc2_w, const float* __restrict__ fc2_b,
                            float* __restrict__ out)            // [5]
{
    const int lane = threadIdx.x;   // 64 threads
    __shared__ float zz[9];
    __shared__ float hh[64];

    if (lane < 2) {
        float sacc = fce_b[lane];
        for (int j = 0; j < 64; ++j) sacc += fce_w[lane * 64 + j] * hlast[j];
        zz[lane] = sacc;
    } else if (lane < 4) {
        int r = lane - 2;
        float sacc = fco_b[r];
        for (int j = 0; j < 64; ++j) sacc += fco_w[r * 64 + j] * hlast[64 + j];
        zz[lane] = sacc;
    } else if (lane < 9) {
        zz[lane] = z[lane - 4];
    }
    __syncthreads();

    float sacc = fc1_b[lane];
#pragma unroll
    for (int j = 0; j < 9; ++j) sacc += fc1_w[lane * 9 + j] * zz[j];
    hh[lane] = fmaxf(sacc, 0.f);
    __syncthreads();

    if (lane < 5) {
        float o = fc2_b[lane];
        for (int i = 0; i < 64; ++i) o += fc2_w[lane * 64 + i] * hh[i];
        out[lane] = o;
    }
}

// ---------------------------------------------------------------------------
extern "C" void kernel_launch(void* const* d_in, const int* in_sizes, int n_in,
                              void* d_out, int out_size, void* d_ws, size_t ws_size,
                              hipStream_t stream)
{
    const float* x      = (const float*)d_in[0];
    const float* y      = (const float*)d_in[1];
    const float* z      = (const float*)d_in[2];
    const float* e_Wih0 = (const float*)d_in[3];
    const float* e_Whh0 = (const float*)d_in[4];
    const float* e_bih0 = (const float*)d_in[5];
    const float* e_bhh0 = (const float*)d_in[6];
    const float* e_Wih1 = (const float*)d_in[7];
    const float* e_Whh1 = (const float*)d_in[8];
    const float* e_bih1 = (const float*)d_in[9];
    const float* e_bhh1 = (const float*)d_in[10];
    const float* o_Wih0 = (const float*)d_in[11];
    const float* o_Whh0 = (const float*)d_in[12];
    const float* o_bih0 = (const float*)d_in[13];
    const float* o_bhh0 = (const float*)d_in[14];
    const float* o_Wih1 = (const float*)d_in[15];
    const float* o_Whh1 = (const float*)d_in[16];
    const float* o_bih1 = (const float*)d_in[17];
    const float* o_bhh1 = (const float*)d_in[18];
    const float* fce_w  = (const float*)d_in[19];
    const float* fce_b  = (const float*)d_in[20];
    const float* fco_w  = (const float*)d_in[21];
    const float* fco_b  = (const float*)d_in[22];
    const float* fc1_w  = (const float*)d_in[23];
    const float* fc1_b  = (const float*)d_in[24];
    const float* fc2_w  = (const float*)d_in[25];
    const float* fc2_b  = (const float*)d_in[26];

    float* pre   = (float*)d_ws;            // 2*T*64 floats = 2 MB
    float* hlast = pre + 2 * T * 64;        // 128 floats
    float* out   = (float*)d_out;

    prep_kernel<<<(2 * T * 64) / 256, 256, 0, stream>>>(
        x, y, e_Wih0, e_bih0, e_bhh0, o_Wih0, o_bih0, o_bhh0, pre);

    seq_kernel<<<2, 128, 0, stream>>>(
        pre,
        e_Whh0, e_Wih1, e_Whh1, e_bih1, e_bhh1,
        o_Whh0, o_Wih1, o_Whh1, o_bih1, o_bhh1,
        hlast);

    head_kernel<<<1, 64, 0, stream>>>(
        hlast, z, fce_w, fce_b, fco_w, fco_b, fc1_w, fc1_b, fc2_w, fc2_b, out);
}